// Round 13
// baseline (429.993 us; speedup 1.0000x reference)
//
#include <hip/hip_runtime.h>
#include <stdint.h>

// ============================================================================
// LaneGraphConvLayerShared: NNConv(edge-conditioned) + root + residual + LN
//
// msg[e,f] = sum_s a[e,s]*(x[src]@W_s)[f] + (x[src]@Bb)[f]
//
// R12 post-mortem: bf16 gather moved the wall (63->53us, FETCH 22->13.9MB).
//   Remaining overhead: per-slot A-rebuild (~384 VALU/wave/tile, serial
//   mul->cvt->MFMA chains) and f32 x_lds keeping LDS at 56.8KB (2 blocks/CU).
// R13: (1) x_lds holds RAW bf16 (staging writes gathered uint4s untouched);
//   A-frags are plain ds_read_b128; a-scaling moves to MFMA OUTPUT (R7 math,
//   f32 fma) -> A-build VALU eliminated. (2) LDS 49.4KB -> 3 blocks/CU
//   (occupancy +50%). B per-si from L2-hot w2frag (no Breg residency trap),
//   launch_bounds(256,3). Everything else = R12 (slot-split, red-reduce,
//   line-coalesced atomics, deferred-stage prefetch, bf16 gather + fallback).
// ============================================================================

typedef short short8 __attribute__((ext_vector_type(8)));
typedef float floatx4 __attribute__((ext_vector_type(4)));

union AFrag { short8 s8; uint32_t u[4]; };

__device__ __forceinline__ uint32_t cvt_pk_bf16(float lo, float hi) {
  uint32_t r;
  asm("v_cvt_pk_bf16_f32 %0, %1, %2" : "=v"(r) : "v"(lo), "v"(hi));
  return r;
}

__device__ __forceinline__ uint16_t f32_to_bf16_bits(float x) {
  uint32_t u = __float_as_uint(x);
  u += 0x7fffu + ((u >> 16) & 1u);
  return (uint16_t)(u >> 16);
}

// ws layout:
//   [0,       139264): W2frag  bf16 [slot17][kstep2][c4][lane64][i8]
//   [139776,  147968): Wsumfrag bf16 (W_root+W_res)
//   [147968,  148224): bsum f32 [64]  (bias + b_res)
//   [148480, +N*128 ): x_bf16 [N][64]   (if ws_size permits)
#define W2FRAG_OFF 0
#define WSUM_OFF   139776
#define BSUM_OFF   147968
#define XBF_OFF    148480
#define PREP_TOTAL 73792   // 69632 + 4096 + 64

__global__ __launch_bounds__(256) void prep_kernel(
    const float* __restrict__ W_edge, const float* __restrict__ b_edge,
    const float* __restrict__ W_root, const float* __restrict__ bias,
    const float* __restrict__ W_res,  const float* __restrict__ b_res,
    uint16_t* __restrict__ w2frag, uint16_t* __restrict__ wsumfrag,
    float* __restrict__ bsum) {
  int gid = blockIdx.x * 256 + threadIdx.x;
  if (gid < 69632) {
    int i = gid & 7, l = (gid >> 3) & 63, c = (gid >> 9) & 3;
    int t = (gid >> 11) & 1, s = gid >> 12;
    int d = t * 32 + 8 * (l >> 4) + i;
    int f = c * 16 + (l & 15);
    float v = (s < 16) ? W_edge[s * 4096 + d * 64 + f] : b_edge[d * 64 + f];
    w2frag[gid] = f32_to_bf16_bits(v);
  } else if (gid < 73728) {
    int g = gid - 69632;
    int i = g & 7, l = (g >> 3) & 63, c = (g >> 9) & 3, t = (g >> 11) & 1;
    int d = t * 32 + 8 * (l >> 4) + i;
    int f = c * 16 + (l & 15);
    wsumfrag[g] = f32_to_bf16_bits(W_root[d * 64 + f] + W_res[d * 64 + f]);
  } else if (gid < PREP_TOTAL) {
    int f = gid - 73728;
    bsum[f] = bias[f] + b_res[f];
  }
}

// base: out = x@(W_root+W_res) + bias+b_res; also emits x_bf16 (frag-order rows)
__global__ __launch_bounds__(256) void base_kernel(
    const float* __restrict__ x, const uint16_t* __restrict__ wsumfrag,
    const float* __restrict__ bsum, float* __restrict__ out,
    uint16_t* __restrict__ xbf, int N) {
  int w = threadIdx.x >> 6, l = threadIdx.x & 63;
  int l16 = l & 15, lq = l >> 4;
  int arow = blockIdx.x * 64 + w * 16 + l16;
  float xv[16];
#pragma unroll
  for (int t = 0; t < 2; ++t)
#pragma unroll
    for (int i = 0; i < 8; ++i)
      xv[t * 8 + i] = (arow < N) ? x[arow * 64 + t * 32 + 8 * lq + i] : 0.0f;
  AFrag A[2];
#pragma unroll
  for (int t = 0; t < 2; ++t)
#pragma unroll
    for (int j = 0; j < 4; ++j)
      A[t].u[j] = cvt_pk_bf16(xv[t * 8 + 2 * j], xv[t * 8 + 2 * j + 1]);
  if (xbf != nullptr && arow < N) {
#pragma unroll
    for (int t = 0; t < 2; ++t) {
      uint4 c;
      c.x = A[t].u[0]; c.y = A[t].u[1]; c.z = A[t].u[2]; c.w = A[t].u[3];
      *(uint4*)(xbf + arow * 64 + t * 32 + lq * 8) = c;
    }
  }
  floatx4 acc[4];
#pragma unroll
  for (int c = 0; c < 4; ++c) acc[c] = (floatx4){0.f, 0.f, 0.f, 0.f};
  const short8* bp = (const short8*)wsumfrag;
#pragma unroll
  for (int t = 0; t < 2; ++t)
#pragma unroll
    for (int c = 0; c < 4; ++c) {
      short8 B = bp[(t * 4 + c) * 64 + l];
      acc[c] = __builtin_amdgcn_mfma_f32_16x16x32_bf16(A[t].s8, B, acc[c], 0, 0, 0);
    }
#pragma unroll
  for (int c = 0; c < 4; ++c) {
    int f = c * 16 + l16;
    float bs = bsum[f];
#pragma unroll
    for (int r = 0; r < 4; ++r) {
      int row = blockIdx.x * 64 + w * 16 + lq * 4 + r;
      if (row < N) out[row * 64 + f] = acc[c][r] + bs;
    }
  }
}

// edge: R12 structure; bf16 x_lds (raw), a-scale on MFMA output, 3 blocks/CU.
template <int XBF>
__global__ __launch_bounds__(256, 3) void edge_kernel(
    const float* __restrict__ x, const uint16_t* __restrict__ xbf,
    const int* __restrict__ eidx, const float* __restrict__ attr,
    const uint16_t* __restrict__ w2frag, float* __restrict__ out, int E) {
  __shared__ __align__(16) uint16_t xb[64][72];  // raw bf16 rows, 9.2KB
  __shared__ float a_lds[64][20];                // 16 slots, padded
  __shared__ int   dst_lds[64];
  __shared__ float red[4][32][68];

  int tid = threadIdx.x;
  int w = tid >> 6, l = tid & 63, l16 = l & 15, lq = l >> 4;
  int row = tid >> 2, q = tid & 3;
  const int* srcp = eidx;
  const int* dstp = eidx + E;
  const float4* x4 = (const float4*)x;
  const uint4* xs4 = (const uint4*)xbf;
  const float4* a4 = (const float4*)attr;
  int T = (E + 63) >> 6;
  const short8* bp = (const short8*)w2frag;

  // ---- stage first tile ----
  int tl = blockIdx.x;
  if (tl < T) {
    int cnt0 = min(64, E - tl * 64);
    bool ok = row < cnt0;
    int sidx = ok ? srcp[tl * 64 + row] : 0;
    uint4 u0 = make_uint4(0, 0, 0, 0), u1 = make_uint4(0, 0, 0, 0);
    if (XBF) {
      if (ok) { u0 = xs4[sidx * 8 + q * 2]; u1 = xs4[sidx * 8 + q * 2 + 1]; }
    } else if (ok) {
      float4 v0 = x4[sidx * 16 + q * 4 + 0], v1 = x4[sidx * 16 + q * 4 + 1];
      float4 v2 = x4[sidx * 16 + q * 4 + 2], v3 = x4[sidx * 16 + q * 4 + 3];
      u0 = make_uint4(cvt_pk_bf16(v0.x, v0.y), cvt_pk_bf16(v0.z, v0.w),
                      cvt_pk_bf16(v1.x, v1.y), cvt_pk_bf16(v1.z, v1.w));
      u1 = make_uint4(cvt_pk_bf16(v2.x, v2.y), cvt_pk_bf16(v2.z, v2.w),
                      cvt_pk_bf16(v3.x, v3.y), cvt_pk_bf16(v3.z, v3.w));
    }
    *(uint4*)&xb[row][q * 16] = u0;
    *(uint4*)&xb[row][q * 16 + 8] = u1;
    float4 av = make_float4(0.f, 0.f, 0.f, 0.f);
    if (ok) av = a4[(tl * 64 + row) * 4 + q];
    *(float4*)&a_lds[row][q * 4] = av;
    if (tid < 64) dst_lds[tid] = (tid < cnt0) ? dstp[tl * 64 + tid] : 0;
  }
  __syncthreads();

  for (; tl < T; tl += gridDim.x) {
    int cnt = min(64, E - tl * 64);
    int nxt = tl + (int)gridDim.x;
    bool havenxt = nxt < T;
    // early-issue next tile's gather (raw words held to stage-write)
    uint4 xu0 = make_uint4(0, 0, 0, 0), xu1 = make_uint4(0, 0, 0, 0);
    float4 ar = make_float4(0.f, 0.f, 0.f, 0.f);
    int dv = 0;
    if (havenxt) {
      int cntn = min(64, E - nxt * 64);
      bool ok = row < cntn;
      int sidx = ok ? srcp[nxt * 64 + row] : 0;
      if (XBF) {
        if (ok) { xu0 = xs4[sidx * 8 + q * 2]; xu1 = xs4[sidx * 8 + q * 2 + 1]; }
      } else if (ok) {
        float4 v0 = x4[sidx * 16 + q * 4 + 0], v1 = x4[sidx * 16 + q * 4 + 1];
        float4 v2 = x4[sidx * 16 + q * 4 + 2], v3 = x4[sidx * 16 + q * 4 + 3];
        xu0 = make_uint4(cvt_pk_bf16(v0.x, v0.y), cvt_pk_bf16(v0.z, v0.w),
                         cvt_pk_bf16(v1.x, v1.y), cvt_pk_bf16(v1.z, v1.w));
        xu1 = make_uint4(cvt_pk_bf16(v2.x, v2.y), cvt_pk_bf16(v2.z, v2.w),
                         cvt_pk_bf16(v3.x, v3.y), cvt_pk_bf16(v3.z, v3.w));
      }
      if (ok) ar = a4[(nxt * 64 + row) * 4 + q];
      if (ok) dv = dstp[nxt * 64 + row];
    }

    // ---- compute: acc[p][rt][c], A raw from LDS, a-scale on MFMA output ----
    floatx4 acc[2][2][4];
#pragma unroll
    for (int p = 0; p < 2; ++p)
#pragma unroll
      for (int rt = 0; rt < 2; ++rt)
#pragma unroll
        for (int c = 0; c < 4; ++c) acc[p][rt][c] = (floatx4){0.f, 0.f, 0.f, 0.f};

#pragma unroll
    for (int si = 0; si < 4; ++si) {
      int s = 4 * si + w;  // this wave's slot
      short8 Bf[2][4];
#pragma unroll
      for (int t = 0; t < 2; ++t)
#pragma unroll
        for (int c = 0; c < 4; ++c)
          Bf[t][c] = bp[((s * 2 + t) * 4 + c) * 64 + l];
#pragma unroll
      for (int p = 0; p < 2; ++p)
#pragma unroll
        for (int rt = 0; rt < 2; ++rt) {
          int arow = p * 32 + rt * 16 + l16;
          short8 A0 = *(const short8*)&xb[arow][lq * 8];
          short8 A1 = *(const short8*)&xb[arow][32 + lq * 8];
          int ab = p * 32 + rt * 16 + lq * 4;
          float av0 = a_lds[ab + 0][s];
          float av1 = a_lds[ab + 1][s];
          float av2 = a_lds[ab + 2][s];
          float av3 = a_lds[ab + 3][s];
#pragma unroll
          for (int c = 0; c < 4; ++c) {
            floatx4 y = (floatx4){0.f, 0.f, 0.f, 0.f};
            y = __builtin_amdgcn_mfma_f32_16x16x32_bf16(A0, Bf[0][c], y, 0, 0, 0);
            y = __builtin_amdgcn_mfma_f32_16x16x32_bf16(A1, Bf[1][c], y, 0, 0, 0);
            acc[p][rt][c][0] += av0 * y[0];
            acc[p][rt][c][1] += av1 * y[1];
            acc[p][rt][c][2] += av2 * y[2];
            acc[p][rt][c][3] += av3 * y[3];
          }
        }
    }
    // bias slot (a==1): waves 2,3 take K-halves
    if (w >= 2) {
      int tx = w - 2;
      short8 Bx[4];
#pragma unroll
      for (int c = 0; c < 4; ++c) Bx[c] = bp[((32 + tx) * 4 + c) * 64 + l];
#pragma unroll
      for (int p = 0; p < 2; ++p)
#pragma unroll
        for (int rt = 0; rt < 2; ++rt) {
          int arow = p * 32 + rt * 16 + l16;
          short8 At = *(const short8*)&xb[arow][tx * 32 + lq * 8];
#pragma unroll
          for (int c = 0; c < 4; ++c) {
            floatx4 y = (floatx4){0.f, 0.f, 0.f, 0.f};
            y = __builtin_amdgcn_mfma_f32_16x16x32_bf16(At, Bx[c], y, 0, 0, 0);
            acc[p][rt][c] += y;
          }
        }
    }

    // ---- per-p: red write, cross-wave reduce + line-coalesced atomics ----
#pragma unroll
    for (int p = 0; p < 2; ++p) {
#pragma unroll
      for (int rt = 0; rt < 2; ++rt)
#pragma unroll
        for (int c = 0; c < 4; ++c) {
          int f = c * 16 + l16;
#pragma unroll
          for (int r = 0; r < 4; ++r)
            red[w][rt * 16 + lq * 4 + r][f] = acc[p][rt][c][r];
        }
      __syncthreads();
#pragma unroll
      for (int c = 0; c < 4; ++c) {
        int f = c * 16 + l16;
#pragma unroll
        for (int r = 0; r < 2; ++r) {
          int rr = w * 8 + lq * 2 + r;
          float s = red[0][rr][f] + red[1][rr][f] + red[2][rr][f] + red[3][rr][f];
          int grow = p * 32 + rr;
          if (grow < cnt) atomicAdd(&out[dst_lds[grow] * 64 + f], s);
        }
      }
      __syncthreads();
    }

    // ---- stage next tile (raw) ----
    if (havenxt) {
      *(uint4*)&xb[row][q * 16] = xu0;
      *(uint4*)&xb[row][q * 16 + 8] = xu1;
      *(float4*)&a_lds[row][q * 4] = ar;
      if (q == 0) dst_lds[row] = dv;
    }
    __syncthreads();
  }
}

__global__ __launch_bounds__(256) void ln_kernel(
    float* __restrict__ out, const float* __restrict__ gamma,
    const float* __restrict__ beta, int N) {
  int w = threadIdx.x >> 6, l = threadIdx.x & 63;
  int row = blockIdx.x * 4 + w;
  if (row >= N) return;
  float v = out[row * 64 + l];
  float s = v;
#pragma unroll
  for (int m = 32; m >= 1; m >>= 1) s += __shfl_xor(s, m);
  float mu = s * 0.015625f;
  float d = v - mu;
  float q = d * d;
#pragma unroll
  for (int m = 32; m >= 1; m >>= 1) q += __shfl_xor(q, m);
  float var = q * 0.015625f;
  out[row * 64 + l] = d * rsqrtf(var + 1e-5f) * gamma[l] + beta[l];
}

extern "C" void kernel_launch(void* const* d_in, const int* in_sizes, int n_in,
                              void* d_out, int out_size, void* d_ws, size_t ws_size,
                              hipStream_t stream) {
  const float* x      = (const float*)d_in[0];
  const int*   eidx   = (const int*)d_in[1];
  const float* attr   = (const float*)d_in[2];
  const float* W_edge = (const float*)d_in[3];
  const float* b_edge = (const float*)d_in[4];
  const float* W_root = (const float*)d_in[5];
  const float* bias   = (const float*)d_in[6];
  const float* W_res  = (const float*)d_in[7];
  const float* b_res  = (const float*)d_in[8];
  const float* gamma  = (const float*)d_in[9];
  const float* beta   = (const float*)d_in[10];
  int N = in_sizes[0] / 64;
  int E = in_sizes[1] / 2;
  float* out = (float*)d_out;
  uint16_t* w2frag   = (uint16_t*)((char*)d_ws + W2FRAG_OFF);
  uint16_t* wsumfrag = (uint16_t*)((char*)d_ws + WSUM_OFF);
  float*    bsum     = (float*)((char*)d_ws + BSUM_OFF);

  size_t need = (size_t)XBF_OFF + (size_t)N * 128;
  bool usebf = ws_size >= need;
  uint16_t* xbf = usebf ? (uint16_t*)((char*)d_ws + XBF_OFF) : nullptr;

  prep_kernel<<<(PREP_TOTAL + 255) / 256, 256, 0, stream>>>(
      W_edge, b_edge, W_root, bias, W_res, b_res, w2frag, wsumfrag, bsum);
  base_kernel<<<(N + 63) / 64, 256, 0, stream>>>(x, wsumfrag, bsum, out, xbf, N);
  int T = (E + 63) / 64;
  int G = T < 512 ? T : 512;
  if (usebf)
    edge_kernel<1><<<G, 256, 0, stream>>>(x, xbf, eidx, attr, w2frag, out, E);
  else
    edge_kernel<0><<<G, 256, 0, stream>>>(x, xbf, eidx, attr, w2frag, out, E);
  ln_kernel<<<(N + 3) / 4, 256, 0, stream>>>(out, gamma, beta, N);
}

// Round 14
// 96.129 us; speedup vs baseline: 4.4731x; 4.4731x over previous
//
#include <hip/hip_runtime.h>
#include <stdint.h>

// ============================================================================
// LaneGraphConvLayerShared: NNConv(edge-conditioned) + root + residual + LN
//
// msg[e,f] = sum_s a[e,s]*(x[src]@W_s)[f] + (x[src]@Bb)[f]
//
// R13 post-mortem: hoisting acc[2][2][4] + launch_bounds(256,3) spilled
//   (cap 170 incl AGPRs; 1.3GB scratch traffic). The raw-bf16-LDS and
//   a-scale-on-output ideas were never actually tested.
// R14: same two ideas on R12's exact register structure:
//   - launch_bounds(256,2), per-p acc[2][4] (32 regs), Breg hoist, identical
//     red-reduce + line-coalesced atomics + deferred-stage prefetch
//   - xb = raw bf16 [64x64] with R7's 16B-chunk XOR swizzle; staging stores
//     gathered uint4s untouched; A = 2x ds_read_b128 per (p,rt)
//   - a-scale on MFMA OUTPUT (f32 fma); bias slot reuses A0/A1 (tx select)
//   LDS 56.8 -> 48.3KB. Per-slot A-rebuild VALU eliminated.
// ============================================================================

typedef short short8 __attribute__((ext_vector_type(8)));
typedef float floatx4 __attribute__((ext_vector_type(4)));

union AFrag { short8 s8; uint32_t u[4]; };

__device__ __forceinline__ uint32_t cvt_pk_bf16(float lo, float hi) {
  uint32_t r;
  asm("v_cvt_pk_bf16_f32 %0, %1, %2" : "=v"(r) : "v"(lo), "v"(hi));
  return r;
}

__device__ __forceinline__ uint16_t f32_to_bf16_bits(float x) {
  uint32_t u = __float_as_uint(x);
  u += 0x7fffu + ((u >> 16) & 1u);
  return (uint16_t)(u >> 16);
}

// ws layout:
//   [0,       139264): W2frag  bf16 [slot17][kstep2][c4][lane64][i8]
//   [139776,  147968): Wsumfrag bf16 (W_root+W_res)
//   [147968,  148224): bsum f32 [64]  (bias + b_res)
//   [148480, +N*128 ): x_bf16 [N][64]   (if ws_size permits)
#define W2FRAG_OFF 0
#define WSUM_OFF   139776
#define BSUM_OFF   147968
#define XBF_OFF    148480
#define PREP_TOTAL 73792   // 69632 + 4096 + 64

__global__ __launch_bounds__(256) void prep_kernel(
    const float* __restrict__ W_edge, const float* __restrict__ b_edge,
    const float* __restrict__ W_root, const float* __restrict__ bias,
    const float* __restrict__ W_res,  const float* __restrict__ b_res,
    uint16_t* __restrict__ w2frag, uint16_t* __restrict__ wsumfrag,
    float* __restrict__ bsum) {
  int gid = blockIdx.x * 256 + threadIdx.x;
  if (gid < 69632) {
    int i = gid & 7, l = (gid >> 3) & 63, c = (gid >> 9) & 3;
    int t = (gid >> 11) & 1, s = gid >> 12;
    int d = t * 32 + 8 * (l >> 4) + i;
    int f = c * 16 + (l & 15);
    float v = (s < 16) ? W_edge[s * 4096 + d * 64 + f] : b_edge[d * 64 + f];
    w2frag[gid] = f32_to_bf16_bits(v);
  } else if (gid < 73728) {
    int g = gid - 69632;
    int i = g & 7, l = (g >> 3) & 63, c = (g >> 9) & 3, t = (g >> 11) & 1;
    int d = t * 32 + 8 * (l >> 4) + i;
    int f = c * 16 + (l & 15);
    wsumfrag[g] = f32_to_bf16_bits(W_root[d * 64 + f] + W_res[d * 64 + f]);
  } else if (gid < PREP_TOTAL) {
    int f = gid - 73728;
    bsum[f] = bias[f] + b_res[f];
  }
}

// base: out = x@(W_root+W_res) + bias+b_res; also emits x_bf16 (frag-order rows)
__global__ __launch_bounds__(256) void base_kernel(
    const float* __restrict__ x, const uint16_t* __restrict__ wsumfrag,
    const float* __restrict__ bsum, float* __restrict__ out,
    uint16_t* __restrict__ xbf, int N) {
  int w = threadIdx.x >> 6, l = threadIdx.x & 63;
  int l16 = l & 15, lq = l >> 4;
  int arow = blockIdx.x * 64 + w * 16 + l16;
  float xv[16];
#pragma unroll
  for (int t = 0; t < 2; ++t)
#pragma unroll
    for (int i = 0; i < 8; ++i)
      xv[t * 8 + i] = (arow < N) ? x[arow * 64 + t * 32 + 8 * lq + i] : 0.0f;
  AFrag A[2];
#pragma unroll
  for (int t = 0; t < 2; ++t)
#pragma unroll
    for (int j = 0; j < 4; ++j)
      A[t].u[j] = cvt_pk_bf16(xv[t * 8 + 2 * j], xv[t * 8 + 2 * j + 1]);
  if (xbf != nullptr && arow < N) {
#pragma unroll
    for (int t = 0; t < 2; ++t) {
      uint4 c;
      c.x = A[t].u[0]; c.y = A[t].u[1]; c.z = A[t].u[2]; c.w = A[t].u[3];
      *(uint4*)(xbf + arow * 64 + t * 32 + lq * 8) = c;
    }
  }
  floatx4 acc[4];
#pragma unroll
  for (int c = 0; c < 4; ++c) acc[c] = (floatx4){0.f, 0.f, 0.f, 0.f};
  const short8* bp = (const short8*)wsumfrag;
#pragma unroll
  for (int t = 0; t < 2; ++t)
#pragma unroll
    for (int c = 0; c < 4; ++c) {
      short8 B = bp[(t * 4 + c) * 64 + l];
      acc[c] = __builtin_amdgcn_mfma_f32_16x16x32_bf16(A[t].s8, B, acc[c], 0, 0, 0);
    }
#pragma unroll
  for (int c = 0; c < 4; ++c) {
    int f = c * 16 + l16;
    float bs = bsum[f];
#pragma unroll
    for (int r = 0; r < 4; ++r) {
      int row = blockIdx.x * 64 + w * 16 + lq * 4 + r;
      if (row < N) out[row * 64 + f] = acc[c][r] + bs;
    }
  }
}

// edge: R12 structure; raw-bf16 swizzled xb, a-scale on MFMA output.
template <int XBF>
__global__ __launch_bounds__(256, 2) void edge_kernel(
    const float* __restrict__ x, const uint16_t* __restrict__ xbf,
    const int* __restrict__ eidx, const float* __restrict__ attr,
    const uint16_t* __restrict__ w2frag, float* __restrict__ out, int E) {
  __shared__ __align__(16) uint16_t xb[64 * 64];  // raw bf16, XOR-swizzled, 8KB
  __shared__ float a_lds[64][20];                 // 16 slots, padded
  __shared__ int   dst_lds[64];
  __shared__ float red[4][32][68];

  int tid = threadIdx.x;
  int w = tid >> 6, l = tid & 63, l16 = l & 15, lq = l >> 4;
  int row = tid >> 2, q = tid & 3;
  const int* srcp = eidx;
  const int* dstp = eidx + E;
  const float4* x4 = (const float4*)x;
  const uint4* xs4 = (const uint4*)xbf;
  const float4* a4 = (const float4*)attr;
  int T = (E + 63) >> 6;
  const short8* bp = (const short8*)w2frag;
  int swzw = (row & 7) << 4;

  // ---- B fragments hoisted (R12-identical) ----
  short8 Breg[4][2][4];
#pragma unroll
  for (int si = 0; si < 4; ++si) {
    int s = 4 * si + w;
#pragma unroll
    for (int t = 0; t < 2; ++t)
#pragma unroll
      for (int c = 0; c < 4; ++c)
        Breg[si][t][c] = bp[((s * 2 + t) * 4 + c) * 64 + l];
  }
  int tx = w - 2;  // waves 2,3 take K-halves of bias slot 16
  short8 Bx[4];
  if (tx >= 0) {
#pragma unroll
    for (int c = 0; c < 4; ++c) Bx[c] = bp[((32 + tx) * 4 + c) * 64 + l];
  }

  // ---- stage first tile ----
  int tl = blockIdx.x;
  if (tl < T) {
    int cnt0 = min(64, E - tl * 64);
    bool ok = row < cnt0;
    int sidx = ok ? srcp[tl * 64 + row] : 0;
    uint4 u0 = make_uint4(0, 0, 0, 0), u1 = make_uint4(0, 0, 0, 0);
    if (XBF) {
      if (ok) { u0 = xs4[sidx * 8 + q * 2]; u1 = xs4[sidx * 8 + q * 2 + 1]; }
    } else if (ok) {
      float4 v0 = x4[sidx * 16 + q * 4 + 0], v1 = x4[sidx * 16 + q * 4 + 1];
      float4 v2 = x4[sidx * 16 + q * 4 + 2], v3 = x4[sidx * 16 + q * 4 + 3];
      u0 = make_uint4(cvt_pk_bf16(v0.x, v0.y), cvt_pk_bf16(v0.z, v0.w),
                      cvt_pk_bf16(v1.x, v1.y), cvt_pk_bf16(v1.z, v1.w));
      u1 = make_uint4(cvt_pk_bf16(v2.x, v2.y), cvt_pk_bf16(v2.z, v2.w),
                      cvt_pk_bf16(v3.x, v3.y), cvt_pk_bf16(v3.z, v3.w));
    }
    *(uint4*)((char*)xb + ((row * 128 + q * 32) ^ swzw)) = u0;
    *(uint4*)((char*)xb + ((row * 128 + q * 32 + 16) ^ swzw)) = u1;
    float4 av = make_float4(0.f, 0.f, 0.f, 0.f);
    if (ok) av = a4[(tl * 64 + row) * 4 + q];
    *(float4*)&a_lds[row][q * 4] = av;
    if (tid < 64) dst_lds[tid] = (tid < cnt0) ? dstp[tl * 64 + tid] : 0;
  }
  __syncthreads();

  for (; tl < T; tl += gridDim.x) {
    int cnt = min(64, E - tl * 64);
    int nxt = tl + (int)gridDim.x;
    bool havenxt = nxt < T;
    // early-issue next tile's gather (raw words held to stage-write)
    uint4 xu0 = make_uint4(0, 0, 0, 0), xu1 = make_uint4(0, 0, 0, 0);
    float4 ar = make_float4(0.f, 0.f, 0.f, 0.f);
    int dv = 0;
    if (havenxt) {
      int cntn = min(64, E - nxt * 64);
      bool ok = row < cntn;
      int sidx = ok ? srcp[nxt * 64 + row] : 0;
      if (XBF) {
        if (ok) { xu0 = xs4[sidx * 8 + q * 2]; xu1 = xs4[sidx * 8 + q * 2 + 1]; }
      } else if (ok) {
        float4 v0 = x4[sidx * 16 + q * 4 + 0], v1 = x4[sidx * 16 + q * 4 + 1];
        float4 v2 = x4[sidx * 16 + q * 4 + 2], v3 = x4[sidx * 16 + q * 4 + 3];
        xu0 = make_uint4(cvt_pk_bf16(v0.x, v0.y), cvt_pk_bf16(v0.z, v0.w),
                         cvt_pk_bf16(v1.x, v1.y), cvt_pk_bf16(v1.z, v1.w));
        xu1 = make_uint4(cvt_pk_bf16(v2.x, v2.y), cvt_pk_bf16(v2.z, v2.w),
                         cvt_pk_bf16(v3.x, v3.y), cvt_pk_bf16(v3.z, v3.w));
      }
      if (ok) ar = a4[(nxt * 64 + row) * 4 + q];
      if (ok) dv = dstp[nxt * 64 + row];
    }

#pragma unroll
    for (int p = 0; p < 2; ++p) {
      floatx4 acc[2][4];
#pragma unroll
      for (int rt = 0; rt < 2; ++rt)
#pragma unroll
        for (int c = 0; c < 4; ++c) acc[rt][c] = (floatx4){0.f, 0.f, 0.f, 0.f};

#pragma unroll
      for (int rt = 0; rt < 2; ++rt) {
        int arow = p * 32 + rt * 16 + l16;
        int swzr = (arow & 7) << 4;
        short8 A0 = *(const short8*)((const char*)xb + ((arow * 128 + lq * 16) ^ swzr));
        short8 A1 = *(const short8*)((const char*)xb + ((arow * 128 + 64 + lq * 16) ^ swzr));
        int ab = p * 32 + rt * 16 + lq * 4;
#pragma unroll
        for (int si = 0; si < 4; ++si) {
          int s = 4 * si + w;
          float av0 = a_lds[ab + 0][s];
          float av1 = a_lds[ab + 1][s];
          float av2 = a_lds[ab + 2][s];
          float av3 = a_lds[ab + 3][s];
#pragma unroll
          for (int c = 0; c < 4; ++c) {
            floatx4 y = (floatx4){0.f, 0.f, 0.f, 0.f};
            y = __builtin_amdgcn_mfma_f32_16x16x32_bf16(A0, Breg[si][0][c], y, 0, 0, 0);
            y = __builtin_amdgcn_mfma_f32_16x16x32_bf16(A1, Breg[si][1][c], y, 0, 0, 0);
            acc[rt][c][0] += av0 * y[0];
            acc[rt][c][1] += av1 * y[1];
            acc[rt][c][2] += av2 * y[2];
            acc[rt][c][3] += av3 * y[3];
          }
        }
        if (tx >= 0) {  // bias slot, a == 1; K-half tx reuses A0/A1
          short8 At = (tx == 0) ? A0 : A1;
#pragma unroll
          for (int c = 0; c < 4; ++c) {
            floatx4 y = (floatx4){0.f, 0.f, 0.f, 0.f};
            y = __builtin_amdgcn_mfma_f32_16x16x32_bf16(At, Bx[c], y, 0, 0, 0);
            acc[rt][c] += y;
          }
        }
      }

      // partial -> LDS
#pragma unroll
      for (int rt = 0; rt < 2; ++rt)
#pragma unroll
        for (int c = 0; c < 4; ++c) {
          int f = c * 16 + l16;
#pragma unroll
          for (int r = 0; r < 4; ++r)
            red[w][rt * 16 + lq * 4 + r][f] = acc[rt][c][r];
        }
      __syncthreads();

      // cross-wave reduce + LINE-COALESCED atomic scatter (R4-verified)
#pragma unroll
      for (int c = 0; c < 4; ++c) {
        int f = c * 16 + l16;
#pragma unroll
        for (int r = 0; r < 2; ++r) {
          int rr = w * 8 + lq * 2 + r;
          float s = red[0][rr][f] + red[1][rr][f] + red[2][rr][f] + red[3][rr][f];
          int grow = p * 32 + rr;
          if (grow < cnt) atomicAdd(&out[dst_lds[grow] * 64 + f], s);
        }
      }
      __syncthreads();
    }

    // stage next tile (raw, swizzled)
    if (havenxt) {
      *(uint4*)((char*)xb + ((row * 128 + q * 32) ^ swzw)) = xu0;
      *(uint4*)((char*)xb + ((row * 128 + q * 32 + 16) ^ swzw)) = xu1;
      *(float4*)&a_lds[row][q * 4] = ar;
      if (q == 0) dst_lds[row] = dv;
    }
    __syncthreads();
  }
}

__global__ __launch_bounds__(256) void ln_kernel(
    float* __restrict__ out, const float* __restrict__ gamma,
    const float* __restrict__ beta, int N) {
  int w = threadIdx.x >> 6, l = threadIdx.x & 63;
  int row = blockIdx.x * 4 + w;
  if (row >= N) return;
  float v = out[row * 64 + l];
  float s = v;
#pragma unroll
  for (int m = 32; m >= 1; m >>= 1) s += __shfl_xor(s, m);
  float mu = s * 0.015625f;
  float d = v - mu;
  float q = d * d;
#pragma unroll
  for (int m = 32; m >= 1; m >>= 1) q += __shfl_xor(q, m);
  float var = q * 0.015625f;
  out[row * 64 + l] = d * rsqrtf(var + 1e-5f) * gamma[l] + beta[l];
}

extern "C" void kernel_launch(void* const* d_in, const int* in_sizes, int n_in,
                              void* d_out, int out_size, void* d_ws, size_t ws_size,
                              hipStream_t stream) {
  const float* x      = (const float*)d_in[0];
  const int*   eidx   = (const int*)d_in[1];
  const float* attr   = (const float*)d_in[2];
  const float* W_edge = (const float*)d_in[3];
  const float* b_edge = (const float*)d_in[4];
  const float* W_root = (const float*)d_in[5];
  const float* bias   = (const float*)d_in[6];
  const float* W_res  = (const float*)d_in[7];
  const float* b_res  = (const float*)d_in[8];
  const float* gamma  = (const float*)d_in[9];
  const float* beta   = (const float*)d_in[10];
  int N = in_sizes[0] / 64;
  int E = in_sizes[1] / 2;
  float* out = (float*)d_out;
  uint16_t* w2frag   = (uint16_t*)((char*)d_ws + W2FRAG_OFF);
  uint16_t* wsumfrag = (uint16_t*)((char*)d_ws + WSUM_OFF);
  float*    bsum     = (float*)((char*)d_ws + BSUM_OFF);

  size_t need = (size_t)XBF_OFF + (size_t)N * 128;
  bool usebf = ws_size >= need;
  uint16_t* xbf = usebf ? (uint16_t*)((char*)d_ws + XBF_OFF) : nullptr;

  prep_kernel<<<(PREP_TOTAL + 255) / 256, 256, 0, stream>>>(
      W_edge, b_edge, W_root, bias, W_res, b_res, w2frag, wsumfrag, bsum);
  base_kernel<<<(N + 63) / 64, 256, 0, stream>>>(x, wsumfrag, bsum, out, xbf, N);
  int T = (E + 63) / 64;
  int G = T < 512 ? T : 512;
  if (usebf)
    edge_kernel<1><<<G, 256, 0, stream>>>(x, xbf, eidx, attr, w2frag, out, E);
  else
    edge_kernel<0><<<G, 256, 0, stream>>>(x, xbf, eidx, attr, w2frag, out, E);
  ln_kernel<<<(N + 3) / 4, 256, 0, stream>>>(out, gamma, beta, N);
}

// Round 17
// 86.888 us; speedup vs baseline: 4.9488x; 1.1064x over previous
//
#include <hip/hip_runtime.h>
#include <stdint.h>

// ============================================================================
// LaneGraphConvLayerShared: NNConv(edge-conditioned) + root + residual + LN
//
// msg[e,f] = (A_e @ W2)[f], A_e[k*64+d]=a[e,k]*x[src,d]; slot16: a=1, b_edge
//
// R14 post-mortem: y-chain restructure spilled (~26MB scratch) -> reverted.
//   R12's exact register structure is the only known-safe one. Remaining
//   lever that doesn't touch registers: occupancy. R12 is LDS-limited
//   (56.8KB -> 2 blocks/CU, 19% occ) while B-load L2 latency dominates.
// R15: R12 byte-identical EXCEPT red stored as bf16 (ushort): LDS 56.8 ->
//   39.5KB -> 4 blocks/CU (VGPR=128 allows 16 waves) -> ~2x latency hiding.
//   Partial-sum bf16 rounding adds ~0.01 absmax (0.031 -> <=0.06 vs 0.0987).
// R16/R17: resubmits (container unresponsive twice; no signal).
// ============================================================================

#define NSLOT 17

typedef short short8 __attribute__((ext_vector_type(8)));
typedef float floatx4 __attribute__((ext_vector_type(4)));

union AFrag { short8 s8; uint32_t u[4]; };

__device__ __forceinline__ uint32_t cvt_pk_bf16(float lo, float hi) {
  uint32_t r;
  asm("v_cvt_pk_bf16_f32 %0, %1, %2" : "=v"(r) : "v"(lo), "v"(hi));
  return r;
}

__device__ __forceinline__ uint16_t f32_to_bf16_bits(float x) {
  uint32_t u = __float_as_uint(x);
  u += 0x7fffu + ((u >> 16) & 1u);
  return (uint16_t)(u >> 16);
}

__device__ __forceinline__ float bf16_bits_to_f32(uint16_t h) {
  return __uint_as_float(((uint32_t)h) << 16);
}

__device__ __forceinline__ float bflo(uint32_t p) { return __uint_as_float(p << 16); }
__device__ __forceinline__ float bfhi(uint32_t p) { return __uint_as_float(p & 0xffff0000u); }

// ws layout:
//   [0,       139264): W2frag  bf16 [slot17][kstep2][c4][lane64][i8]
//   [139776,  147968): Wsumfrag bf16 (W_root+W_res)
//   [147968,  148224): bsum f32 [64]  (bias + b_res)
//   [148480, +N*128 ): x_bf16 [N][64]   (if ws_size permits)
#define W2FRAG_OFF 0
#define WSUM_OFF   139776
#define BSUM_OFF   147968
#define XBF_OFF    148480
#define PREP_TOTAL 73792   // 69632 + 4096 + 64

__global__ __launch_bounds__(256) void prep_kernel(
    const float* __restrict__ W_edge, const float* __restrict__ b_edge,
    const float* __restrict__ W_root, const float* __restrict__ bias,
    const float* __restrict__ W_res,  const float* __restrict__ b_res,
    uint16_t* __restrict__ w2frag, uint16_t* __restrict__ wsumfrag,
    float* __restrict__ bsum) {
  int gid = blockIdx.x * 256 + threadIdx.x;
  if (gid < 69632) {
    int i = gid & 7, l = (gid >> 3) & 63, c = (gid >> 9) & 3;
    int t = (gid >> 11) & 1, s = gid >> 12;
    int d = t * 32 + 8 * (l >> 4) + i;
    int f = c * 16 + (l & 15);
    float v = (s < 16) ? W_edge[s * 4096 + d * 64 + f] : b_edge[d * 64 + f];
    w2frag[gid] = f32_to_bf16_bits(v);
  } else if (gid < 73728) {
    int g = gid - 69632;
    int i = g & 7, l = (g >> 3) & 63, c = (g >> 9) & 3, t = (g >> 11) & 1;
    int d = t * 32 + 8 * (l >> 4) + i;
    int f = c * 16 + (l & 15);
    wsumfrag[g] = f32_to_bf16_bits(W_root[d * 64 + f] + W_res[d * 64 + f]);
  } else if (gid < PREP_TOTAL) {
    int f = gid - 73728;
    bsum[f] = bias[f] + b_res[f];
  }
}

// base: out = x@(W_root+W_res) + bias+b_res; also emits x_bf16.
__global__ __launch_bounds__(256) void base_kernel(
    const float* __restrict__ x, const uint16_t* __restrict__ wsumfrag,
    const float* __restrict__ bsum, float* __restrict__ out,
    uint16_t* __restrict__ xbf, int N) {
  int w = threadIdx.x >> 6, l = threadIdx.x & 63;
  int l16 = l & 15, lq = l >> 4;
  int arow = blockIdx.x * 64 + w * 16 + l16;
  float xv[16];
#pragma unroll
  for (int t = 0; t < 2; ++t)
#pragma unroll
    for (int i = 0; i < 8; ++i)
      xv[t * 8 + i] = (arow < N) ? x[arow * 64 + t * 32 + 8 * lq + i] : 0.0f;
  AFrag A[2];
#pragma unroll
  for (int t = 0; t < 2; ++t)
#pragma unroll
    for (int j = 0; j < 4; ++j)
      A[t].u[j] = cvt_pk_bf16(xv[t * 8 + 2 * j], xv[t * 8 + 2 * j + 1]);
  if (xbf != nullptr && arow < N) {
#pragma unroll
    for (int t = 0; t < 2; ++t) {
      uint4 c;
      c.x = A[t].u[0]; c.y = A[t].u[1]; c.z = A[t].u[2]; c.w = A[t].u[3];
      *(uint4*)(xbf + arow * 64 + t * 32 + lq * 8) = c;
    }
  }
  floatx4 acc[4];
#pragma unroll
  for (int c = 0; c < 4; ++c) acc[c] = (floatx4){0.f, 0.f, 0.f, 0.f};
  const short8* bp = (const short8*)wsumfrag;
#pragma unroll
  for (int t = 0; t < 2; ++t)
#pragma unroll
    for (int c = 0; c < 4; ++c) {
      short8 B = bp[(t * 4 + c) * 64 + l];
      acc[c] = __builtin_amdgcn_mfma_f32_16x16x32_bf16(A[t].s8, B, acc[c], 0, 0, 0);
    }
#pragma unroll
  for (int c = 0; c < 4; ++c) {
    int f = c * 16 + l16;
    float bs = bsum[f];
#pragma unroll
    for (int r = 0; r < 4; ++r) {
      int row = blockIdx.x * 64 + w * 16 + lq * 4 + r;
      if (row < N) out[row * 64 + f] = acc[c][r] + bs;
    }
  }
}

// edge: R12 structure verbatim; red stored as bf16 -> LDS 39.5KB, 4 blocks/CU.
template <int XBF>
__global__ __launch_bounds__(256, 2) void edge_kernel(
    const float* __restrict__ x, const uint16_t* __restrict__ xbf,
    const int* __restrict__ eidx, const float* __restrict__ attr,
    const uint16_t* __restrict__ w2frag, float* __restrict__ out, int E) {
  __shared__ float x_lds[64][68];
  __shared__ float a_lds[64][17];
  __shared__ int   dst_lds[64];
  __shared__ uint16_t red[4][32][68];   // bf16 partials

  int tid = threadIdx.x;
  int w = tid >> 6, l = tid & 63, l16 = l & 15, lq = l >> 4;
  int row = tid >> 2, q = tid & 3;
  const int* srcp = eidx;
  const int* dstp = eidx + E;
  const float4* x4 = (const float4*)x;
  const uint4* xs4 = (const uint4*)xbf;
  const float4* a4 = (const float4*)attr;
  int T = (E + 63) >> 6;
  const short8* bp = (const short8*)w2frag;

  short8 Breg[4][2][4];
#pragma unroll
  for (int si = 0; si < 4; ++si) {
    int s = 4 * si + w;
#pragma unroll
    for (int t = 0; t < 2; ++t)
#pragma unroll
      for (int c = 0; c < 4; ++c)
        Breg[si][t][c] = bp[((s * 2 + t) * 4 + c) * 64 + l];
  }
  int tx = w - 2;  // waves 2,3 take K-halves of bias slot 16
  short8 Bx[4];
  if (tx >= 0) {
#pragma unroll
    for (int c = 0; c < 4; ++c) Bx[c] = bp[((32 + tx) * 4 + c) * 64 + l];
  }

  // ---- stage first tile ----
  int tl = blockIdx.x;
  if (tl < T) {
    int cnt0 = min(64, E - tl * 64);
    bool ok = row < cnt0;
    int sidx = ok ? srcp[tl * 64 + row] : 0;
    if (XBF) {
      uint4 u0 = make_uint4(0, 0, 0, 0), u1 = make_uint4(0, 0, 0, 0);
      if (ok) { u0 = xs4[sidx * 8 + q * 2]; u1 = xs4[sidx * 8 + q * 2 + 1]; }
      uint32_t uu[8] = {u0.x, u0.y, u0.z, u0.w, u1.x, u1.y, u1.z, u1.w};
#pragma unroll
      for (int j = 0; j < 4; ++j) {
        float4 v = make_float4(bflo(uu[2 * j]), bfhi(uu[2 * j]),
                               bflo(uu[2 * j + 1]), bfhi(uu[2 * j + 1]));
        *(float4*)&x_lds[row][q * 16 + j * 4] = v;
      }
    } else {
#pragma unroll
      for (int j = 0; j < 4; ++j) {
        float4 v = make_float4(0.f, 0.f, 0.f, 0.f);
        if (ok) v = x4[sidx * 16 + q * 4 + j];
        *(float4*)&x_lds[row][q * 16 + j * 4] = v;
      }
    }
    float4 av = make_float4(0.f, 0.f, 0.f, 0.f);
    if (ok) av = a4[(tl * 64 + row) * 4 + q];
    a_lds[row][q * 4 + 0] = av.x;
    a_lds[row][q * 4 + 1] = av.y;
    a_lds[row][q * 4 + 2] = av.z;
    a_lds[row][q * 4 + 3] = av.w;
    if (q == 0) a_lds[row][16] = 1.0f;
    if (tid < 64) dst_lds[tid] = (tid < cnt0) ? dstp[tl * 64 + tid] : 0;
  }
  __syncthreads();

  for (; tl < T; tl += gridDim.x) {
    int cnt = min(64, E - tl * 64);
    int nxt = tl + (int)gridDim.x;
    bool havenxt = nxt < T;
    // early-issue next tile's gather; raw words held, expanded at stage-write
    float4 xr[4];
    uint4 xu0 = make_uint4(0, 0, 0, 0), xu1 = make_uint4(0, 0, 0, 0);
    float4 ar = make_float4(0.f, 0.f, 0.f, 0.f);
    int dv = 0;
    if (havenxt) {
      int cntn = min(64, E - nxt * 64);
      bool ok = row < cntn;
      int sidx = ok ? srcp[nxt * 64 + row] : 0;
      if (XBF) {
        if (ok) { xu0 = xs4[sidx * 8 + q * 2]; xu1 = xs4[sidx * 8 + q * 2 + 1]; }
      } else {
#pragma unroll
        for (int j = 0; j < 4; ++j) {
          xr[j] = make_float4(0.f, 0.f, 0.f, 0.f);
          if (ok) xr[j] = x4[sidx * 16 + q * 4 + j];
        }
      }
      if (ok) ar = a4[(nxt * 64 + row) * 4 + q];
      if (ok) dv = dstp[nxt * 64 + row];
    }

#pragma unroll
    for (int p = 0; p < 2; ++p) {
      floatx4 acc[2][4];
#pragma unroll
      for (int rt = 0; rt < 2; ++rt)
#pragma unroll
        for (int c = 0; c < 4; ++c) acc[rt][c] = (floatx4){0.f, 0.f, 0.f, 0.f};

#pragma unroll
      for (int rt = 0; rt < 2; ++rt) {
        int arow = p * 32 + rt * 16 + l16;
        float xv[16];
#pragma unroll
        for (int t2 = 0; t2 < 2; ++t2)
#pragma unroll
          for (int i = 0; i < 8; ++i)
            xv[t2 * 8 + i] = x_lds[arow][t2 * 32 + 8 * lq + i];
#pragma unroll
        for (int si = 0; si < 4; ++si) {
          float av = a_lds[arow][4 * si + w];
#pragma unroll
          for (int t = 0; t < 2; ++t) {
            AFrag A;
#pragma unroll
            for (int j = 0; j < 4; ++j)
              A.u[j] = cvt_pk_bf16(av * xv[t * 8 + 2 * j], av * xv[t * 8 + 2 * j + 1]);
#pragma unroll
            for (int c = 0; c < 4; ++c)
              acc[rt][c] = __builtin_amdgcn_mfma_f32_16x16x32_bf16(
                  A.s8, Breg[si][t][c], acc[rt][c], 0, 0, 0);
          }
        }
        if (tx >= 0) {  // bias slot, a == 1, K-half tx
          AFrag A;
#pragma unroll
          for (int j = 0; j < 4; ++j)
            A.u[j] = cvt_pk_bf16(xv[tx * 8 + 2 * j], xv[tx * 8 + 2 * j + 1]);
#pragma unroll
          for (int c = 0; c < 4; ++c)
            acc[rt][c] = __builtin_amdgcn_mfma_f32_16x16x32_bf16(
                A.s8, Bx[c], acc[rt][c], 0, 0, 0);
        }
      }

      // partial -> LDS (bf16)
#pragma unroll
      for (int rt = 0; rt < 2; ++rt)
#pragma unroll
        for (int c = 0; c < 4; ++c) {
          int f = c * 16 + l16;
#pragma unroll
          for (int r = 0; r < 4; ++r)
            red[w][rt * 16 + lq * 4 + r][f] = f32_to_bf16_bits(acc[rt][c][r]);
        }
      __syncthreads();

      // cross-wave reduce (bf16 -> f32) + LINE-COALESCED atomic scatter
#pragma unroll
      for (int c = 0; c < 4; ++c) {
        int f = c * 16 + l16;
#pragma unroll
        for (int r = 0; r < 2; ++r) {
          int rr = w * 8 + lq * 2 + r;
          float s = bf16_bits_to_f32(red[0][rr][f]) + bf16_bits_to_f32(red[1][rr][f]) +
                    bf16_bits_to_f32(red[2][rr][f]) + bf16_bits_to_f32(red[3][rr][f]);
          int grow = p * 32 + rr;
          if (grow < cnt) atomicAdd(&out[dst_lds[grow] * 64 + f], s);
        }
      }
      __syncthreads();
    }

    // stage next tile (all reads of current tile complete)
    if (havenxt) {
      if (XBF) {
        uint32_t uu[8] = {xu0.x, xu0.y, xu0.z, xu0.w, xu1.x, xu1.y, xu1.z, xu1.w};
#pragma unroll
        for (int j = 0; j < 4; ++j) {
          float4 v = make_float4(bflo(uu[2 * j]), bfhi(uu[2 * j]),
                                 bflo(uu[2 * j + 1]), bfhi(uu[2 * j + 1]));
          *(float4*)&x_lds[row][q * 16 + j * 4] = v;
        }
      } else {
#pragma unroll
        for (int j = 0; j < 4; ++j) *(float4*)&x_lds[row][q * 16 + j * 4] = xr[j];
      }
      a_lds[row][q * 4 + 0] = ar.x;
      a_lds[row][q * 4 + 1] = ar.y;
      a_lds[row][q * 4 + 2] = ar.z;
      a_lds[row][q * 4 + 3] = ar.w;
      if (q == 0) dst_lds[row] = dv;
    }
    __syncthreads();
  }
}

__global__ __launch_bounds__(256) void ln_kernel(
    float* __restrict__ out, const float* __restrict__ gamma,
    const float* __restrict__ beta, int N) {
  int w = threadIdx.x >> 6, l = threadIdx.x & 63;
  int row = blockIdx.x * 4 + w;
  if (row >= N) return;
  float v = out[row * 64 + l];
  float s = v;
#pragma unroll
  for (int m = 32; m >= 1; m >>= 1) s += __shfl_xor(s, m);
  float mu = s * 0.015625f;
  float d = v - mu;
  float q = d * d;
#pragma unroll
  for (int m = 32; m >= 1; m >>= 1) q += __shfl_xor(q, m);
  float var = q * 0.015625f;
  out[row * 64 + l] = d * rsqrtf(var + 1e-5f) * gamma[l] + beta[l];
}

extern "C" void kernel_launch(void* const* d_in, const int* in_sizes, int n_in,
                              void* d_out, int out_size, void* d_ws, size_t ws_size,
                              hipStream_t stream) {
  const float* x      = (const float*)d_in[0];
  const int*   eidx   = (const int*)d_in[1];
  const float* attr   = (const float*)d_in[2];
  const float* W_edge = (const float*)d_in[3];
  const float* b_edge = (const float*)d_in[4];
  const float* W_root = (const float*)d_in[5];
  const float* bias   = (const float*)d_in[6];
  const float* W_res  = (const float*)d_in[7];
  const float* b_res  = (const float*)d_in[8];
  const float* gamma  = (const float*)d_in[9];
  const float* beta   = (const float*)d_in[10];
  int N = in_sizes[0] / 64;
  int E = in_sizes[1] / 2;
  float* out = (float*)d_out;
  uint16_t* w2frag   = (uint16_t*)((char*)d_ws + W2FRAG_OFF);
  uint16_t* wsumfrag = (uint16_t*)((char*)d_ws + WSUM_OFF);
  float*    bsum     = (float*)((char*)d_ws + BSUM_OFF);

  size_t need = (size_t)XBF_OFF + (size_t)N * 128;
  bool usebf = ws_size >= need;
  uint16_t* xbf = usebf ? (uint16_t*)((char*)d_ws + XBF_OFF) : nullptr;

  prep_kernel<<<(PREP_TOTAL + 255) / 256, 256, 0, stream>>>(
      W_edge, b_edge, W_root, bias, W_res, b_res, w2frag, wsumfrag, bsum);
  base_kernel<<<(N + 63) / 64, 256, 0, stream>>>(x, wsumfrag, bsum, out, xbf, N);
  int T = (E + 63) / 64;
  int G = T < 512 ? T : 512;
  if (usebf)
    edge_kernel<1><<<G, 256, 0, stream>>>(x, xbf, eidx, attr, w2frag, out, E);
  else
    edge_kernel<0><<<G, 256, 0, stream>>>(x, xbf, eidx, attr, w2frag, out, E);
  ln_kernel<<<(N + 3) / 4, 256, 0, stream>>>(out, gamma, beta, N);
}